// Round 2
// baseline (108.540 us; speedup 1.0000x reference)
//
#include <hip/hip_runtime.h>
#include <math.h>
#include <float.h>

// Problem constants
#define B_ 64
#define M_ 16
#define A_ 128
#define H_ 128
#define P_ 16
#define NAT 100
#define NFP 2048
#define ZDIM (H_ + P_)   // 144

// Scratch in static device globals — no reliance on ws_size.
__device__ float g_Ta[NAT * H_];       //  51 KB
__device__ float g_Tf[NFP * H_];       //   1 MB
__device__ float g_mol[B_ * M_ * H_];  // 512 KB

// K1: T_a[r,:] = atom_emb[r,:] @ W_in[0:128,:]   (r < 100)
//     T_f[r,:] = fp_emb[r,:]   @ W_in[128:256,:] (r < 2048)
// One block per table row, 128 threads (thread j = output col).
__global__ void k1_precompute(const float* __restrict__ atom_emb,
                              const float* __restrict__ fp_emb,
                              const float* __restrict__ W_in) {
    __shared__ float e[H_];
    const int r = blockIdx.x, j = threadIdx.x;
    const float* emb;
    const float* W;
    float* out;
    if (r < NAT) { emb = atom_emb + r * H_; W = W_in;             out = g_Ta + r * H_; }
    else { int rf = r - NAT; emb = fp_emb + rf * H_; W = W_in + H_ * H_; out = g_Tf + rf * H_; }
    e[j] = emb[j];
    __syncthreads();
    float acc = 0.f;
#pragma unroll 8
    for (int k = 0; k < H_; ++k) acc += e[k] * W[k * H_ + j];
    out[j] = acc;
}

// K2: mol[bm, j] = mean_a relu(T_a[af[bm,a], j] + T_f[fp[bm,a], j] + b_in[j])
// One block per (b,m), 128 threads.
__global__ void k2_mol(const int* __restrict__ af, const int* __restrict__ fpi,
                       const float* __restrict__ b_in) {
    __shared__ int ia[A_];
    __shared__ int ifp[A_];
    const int bm = blockIdx.x, j = threadIdx.x;
    ia[j]  = af[bm * A_ + j];
    ifp[j] = fpi[bm * A_ + j];
    __syncthreads();
    const float bj = b_in[j];
    float acc = 0.f;
#pragma unroll 8
    for (int a = 0; a < A_; ++a) {
        float v = g_Ta[ia[a] * H_ + j] + g_Tf[ifp[a] * H_ + j] + bj;
        acc += fmaxf(v, 0.f);
    }
    g_mol[bm * H_ + j] = acc * (1.0f / (float)A_);
}

// K3: per-batch mix + LayerNorm + MLP head. One block per b, 128 threads.
__global__ void k3_head(const float* __restrict__ phys,
                        const float* __restrict__ ratios,
                        const float* __restrict__ ln_g,
                        const float* __restrict__ ln_b,
                        const float* __restrict__ W1,
                        const float* __restrict__ b1,
                        const float* __restrict__ W2,
                        const float* __restrict__ b2,
                        float* __restrict__ out) {
    const int b = blockIdx.x, j = threadIdx.x;
    __shared__ float w[M_];
    __shared__ float z[ZDIM];
    __shared__ float zn[ZDIM];
    __shared__ float red[H_];

    if (j < M_) w[j] = ratios[b * M_ + j];
    __syncthreads();

    float rsum = 0.f;
#pragma unroll
    for (int m = 0; m < M_; ++m) rsum += w[m];
    const float dinv = 1.0f / (rsum + 1e-8f);

    // mix_h
    float acc = 0.f;
#pragma unroll
    for (int m = 0; m < M_; ++m) acc += (w[m] * dinv) * g_mol[(b * M_ + m) * H_ + j];
    z[j] = acc;

    // mix_p (threads 0..15)
    if (j < P_) {
        float accp = 0.f;
#pragma unroll
        for (int m = 0; m < M_; ++m) {
            float pv = phys[(b * M_ + m) * P_ + j];
            if (isnan(pv)) pv = 0.f;
            else if (isinf(pv)) pv = (pv > 0.f) ? 1000.f : -1000.f;
            accp += (w[m] * dinv) * pv;
        }
        z[H_ + j] = accp;
    }
    __syncthreads();

    // LayerNorm stats (redundant per-thread; broadcast LDS reads, cheap)
    float s = 0.f;
#pragma unroll 8
    for (int k = 0; k < ZDIM; ++k) s += z[k];
    const float mu = s * (1.0f / (float)ZDIM);
    float s2 = 0.f;
#pragma unroll 8
    for (int k = 0; k < ZDIM; ++k) { float d = z[k] - mu; s2 += d * d; }
    const float rstd = rsqrtf(s2 * (1.0f / (float)ZDIM) + 1e-5f);

    for (int k = j; k < ZDIM; k += H_)
        zn[k] = (z[k] - mu) * rstd * ln_g[k] + ln_b[k];
    __syncthreads();

    // h1 = relu(zn @ W1 + b1); thread j = column j
    float a1 = 0.f;
#pragma unroll 8
    for (int k = 0; k < ZDIM; ++k) a1 += zn[k] * W1[k * H_ + j];
    const float h1 = fmaxf(a1 + b1[j], 0.f);
    red[j] = h1 * W2[j];
    __syncthreads();

    if (j == 0) {
        float y = b2[0];
#pragma unroll 8
        for (int k = 0; k < H_; ++k) y += red[k];
        // jnp.nan_to_num: nan->0, +inf->FLT_MAX, -inf->-FLT_MAX
        if (isnan(y)) y = 0.f;
        else if (isinf(y)) y = (y > 0.f) ? FLT_MAX : -FLT_MAX;
        out[b] = y;
    }
}

extern "C" void kernel_launch(void* const* d_in, const int* in_sizes, int n_in,
                              void* d_out, int out_size, void* d_ws, size_t ws_size,
                              hipStream_t stream) {
    const int*   af    = (const int*)d_in[0];
    const int*   fpi   = (const int*)d_in[1];
    const float* phys  = (const float*)d_in[2];
    const float* ratio = (const float*)d_in[3];
    const float* aemb  = (const float*)d_in[4];
    const float* femb  = (const float*)d_in[5];
    const float* W_in  = (const float*)d_in[6];
    const float* b_in  = (const float*)d_in[7];
    const float* ln_g  = (const float*)d_in[8];
    const float* ln_b  = (const float*)d_in[9];
    const float* W1    = (const float*)d_in[10];
    const float* b1    = (const float*)d_in[11];
    const float* W2    = (const float*)d_in[12];
    const float* b2    = (const float*)d_in[13];
    float* out = (float*)d_out;

    k1_precompute<<<dim3(NAT + NFP), dim3(H_), 0, stream>>>(aemb, femb, W_in);
    k2_mol<<<dim3(B_ * M_), dim3(H_), 0, stream>>>(af, fpi, b_in);
    k3_head<<<dim3(B_), dim3(H_), 0, stream>>>(phys, ratio, ln_g, ln_b, W1, b1, W2, b2, out);
}